// Round 17
// baseline (355.294 us; speedup 1.0000x reference)
//
#include <hip/hip_runtime.h>
#include <stdint.h>

typedef __attribute__((ext_vector_type(8))) short short8;
typedef __attribute__((ext_vector_type(4))) float f32x4;

#define NNODES 55296
#define DOUT 256

#define WAIT_VM(N) asm volatile("s_waitcnt vmcnt(" #N ")" ::: "memory")
#define SOFT_FENCE asm volatile("" ::: "memory")

__device__ __forceinline__ float bf2f(unsigned short h) {
    union { unsigned u; float f; } x; x.u = ((unsigned)h) << 16; return x.f;
}
__device__ __forceinline__ unsigned short f2bf(float f) {
    union { float f; unsigned u; } x; x.f = f;
    return (unsigned short)((x.u + 0x7fffu + ((x.u >> 16) & 1u)) >> 16);
}

__device__ __forceinline__ void storev(float* p, float v) { *p = v; }
__device__ __forceinline__ void storev(unsigned short* p, float v) { *p = f2bf(v); }

__device__ __forceinline__ void dma16(const void* g, void* l) {
    __builtin_amdgcn_global_load_lds(
        reinterpret_cast<const unsigned int __attribute__((address_space(1)))*>((uintptr_t)g),
        reinterpret_cast<unsigned int __attribute__((address_space(3)))*>((uintptr_t)l),
        16, 0, 0);
}

// ---- fragment helpers (v3 fallback + mean kernels) ----
__device__ __forceinline__ short8 frag_self(const float* p) {
    float4 a = *(const float4*)p, b = *(const float4*)(p + 4);
    union { short8 s; unsigned short u[8]; } r;
    r.u[0] = f2bf(a.x); r.u[1] = f2bf(a.y); r.u[2] = f2bf(a.z); r.u[3] = f2bf(a.w);
    r.u[4] = f2bf(b.x); r.u[5] = f2bf(b.y); r.u[6] = f2bf(b.z); r.u[7] = f2bf(b.w);
    return r.s;
}
__device__ __forceinline__ short8 frag_self(const unsigned short* p) {
    return *(const short8*)p;
}
__device__ __forceinline__ void acc8(const float* p, float* o) {
    float4 a = *(const float4*)p, b = *(const float4*)(p + 4);
    o[0] += a.x; o[1] += a.y; o[2] += a.z; o[3] += a.w;
    o[4] += b.x; o[5] += b.y; o[6] += b.z; o[7] += b.w;
}
__device__ __forceinline__ void acc8(const unsigned short* p, float* o) {
    uint4 v = *(const uint4*)p;
    const unsigned short* u = (const unsigned short*)&v;
#pragma unroll
    for (int i = 0; i < 8; ++i) o[i] += bf2f(u[i]);
}
template <typename TIN>
__device__ __forceinline__ short8 frag_mean4(const TIN* p0, const TIN* p1,
                                             const TIN* p2, const TIN* p3) {
    float s[8] = {0.f, 0.f, 0.f, 0.f, 0.f, 0.f, 0.f, 0.f};
    acc8(p0, s); acc8(p1, s); acc8(p2, s); acc8(p3, s);
    union { short8 s8; unsigned short u[8]; } r;
#pragma unroll
    for (int i = 0; i < 8; ++i) r.u[i] = f2bf(s[i] * 0.25f);
    return r.s8;
}

// ---- old Wt (d-major) for v3 fallback ----
__global__ void build_wt(const float* __restrict__ Ws,
                         const float* __restrict__ Wn,
                         unsigned short* __restrict__ Wt, int C) {
    int K2 = 2 * C;
    int idx = blockIdx.x * 256 + threadIdx.x;
    if (idx >= 256 * K2) return;
    int d = idx / K2;
    int k = idx - d * K2;
    float v = (k < C) ? Ws[(size_t)k * DOUT + d] : Wn[(size_t)(k - C) * DOUT + d];
    Wt[idx] = f2bf(v);
}

// ---- pair-major pre-swizzled W: Wp[q][col 256][128B], byte kq ^ ((col&7)<<4) ----
__global__ void build_wt_pm(const float* __restrict__ Ws,
                            const float* __restrict__ Wn,
                            unsigned short* __restrict__ Wp, int C) {
    int K2 = 2 * C;
    int idx = blockIdx.x * 256 + threadIdx.x;
    if (idx >= 256 * K2) return;
    int d = idx / K2;
    int k = idx - d * K2;
    float v = (k < C) ? Ws[(size_t)k * DOUT + d] : Wn[(size_t)(k - C) * DOUT + d];
    int q = k >> 6;
    int kqb = (k & 63) * 2;
    int byte = q * 32768 + d * 128 + (kqb ^ ((d & 7) << 4));
    Wp[byte >> 1] = f2bf(v);
}

// ---- layer-1 prep (phase-major): xm_pm[c][M][32 elems]; c<4 self, c>=4 mean ----
__global__ __launch_bounds__(256) void mean_xb_pm(const float* __restrict__ x,
                                                  const int* __restrict__ nbr,
                                                  unsigned short* __restrict__ xm,
                                                  int mTot) {
    const int idx = blockIdx.x * 256 + threadIdx.x;
    const int node = idx >> 4;
    const int ch = (idx & 15) * 8;         // 0..120
    const int b = node / NNODES;
    const int n = node - b * NNODES;
    const size_t bbase = (size_t)b * NNODES;
    const int4 nb = *(const int4*)(nbr + (size_t)n * 4);
    const float* ps = x + (size_t)node * 128 + ch;
    union { uint4 v; unsigned short u[8]; } rs, rm;
    float4 a0 = *(const float4*)ps, a1 = *(const float4*)(ps + 4);
    rs.u[0] = f2bf(a0.x); rs.u[1] = f2bf(a0.y); rs.u[2] = f2bf(a0.z); rs.u[3] = f2bf(a0.w);
    rs.u[4] = f2bf(a1.x); rs.u[5] = f2bf(a1.y); rs.u[6] = f2bf(a1.z); rs.u[7] = f2bf(a1.w);
    float s[8] = {0.f, 0.f, 0.f, 0.f, 0.f, 0.f, 0.f, 0.f};
    acc8(x + (bbase + nb.x) * 128 + ch, s);
    acc8(x + (bbase + nb.y) * 128 + ch, s);
    acc8(x + (bbase + nb.z) * 128 + ch, s);
    acc8(x + (bbase + nb.w) * 128 + ch, s);
#pragma unroll
    for (int i = 0; i < 8; ++i) rm.u[i] = f2bf(s[i] * 0.25f);
    const size_t cs = (size_t)mTot * 32;
    *(uint4*)(xm + (size_t)(ch >> 5) * cs + (size_t)node * 32 + (ch & 31)) = rs.v;
    *(uint4*)(xm + (size_t)(4 + (ch >> 5)) * cs + (size_t)node * 32 + (ch & 31)) = rm.v;
}

// ---- hm_pm[c][M][32] = mean4 of h1_pm (phase-major in AND out) ----
__global__ __launch_bounds__(256) void mean_pass_pm(const unsigned short* __restrict__ h1,
                                                    const int* __restrict__ nbr,
                                                    unsigned short* __restrict__ hm,
                                                    int mTot) {
    const int idx = blockIdx.x * 256 + threadIdx.x;
    const int node = idx >> 5;
    const int ch = (idx & 31) * 8;         // 0..248
    const int b = node / NNODES;
    const int n = node - b * NNODES;
    const size_t bbase = (size_t)b * NNODES;
    const int4 nb = *(const int4*)(nbr + (size_t)n * 4);
    const size_t cs = (size_t)mTot * 32;
    const size_t co = (size_t)(ch >> 5) * cs + (ch & 31);
    float s[8] = {0.f, 0.f, 0.f, 0.f, 0.f, 0.f, 0.f, 0.f};
    acc8(h1 + co + (bbase + nb.x) * 32, s);
    acc8(h1 + co + (bbase + nb.y) * 32, s);
    acc8(h1 + co + (bbase + nb.z) * 32, s);
    acc8(h1 + co + (bbase + nb.w) * 32, s);
    union { uint4 v; unsigned short u[8]; } r;
#pragma unroll
    for (int i = 0; i < 8; ++i) r.u[i] = f2bf(s[i] * 0.25f);
    *(uint4*)(hm + co + (size_t)node * 32) = r.v;
}

// ============================================================================
// v16: A in REGISTERS (phase-major layout makes each fragment a contiguous
//   1KB coalesced load), W in 32KB LDS dbuf via DMA. Per phase:
//   vmcnt(0)+barrier -> issue A(p+1) reg-loads + W(p+1) DMA -> MFMA(p).
//   asm memory-clobber fences stop the compiler sinking the A loads.
//   LDS 32KB -> reg-limited ~3 blocks/CU. Tile 128x128, 4 waves; XCD swizzle.
// ============================================================================
template <int NK, typename TOUT>
__global__ __launch_bounds__(256) void sage_v16(
    const unsigned short* __restrict__ a0p,   // phase-major A chunks [0,8)
    const unsigned short* __restrict__ a1p,   // phase-major A chunks [8,16)
    const unsigned short* __restrict__ Wp,    // [NK q][256 col][128B] pre-swz
    const float* __restrict__ bias,           // [256]
    TOUT* __restrict__ out,                   // h1_pm (bf16) or [M][256] f32
    int nwg, int mTot) {
    extern __shared__ char lds[];
    const int tid = threadIdx.x;
    const int bid = blockIdx.x;
    const int wk = (bid & 7) * (nwg >> 3) + (bid >> 3);  // bijective (nwg%8==0)
    const int yg = wk & 1;
    const int rb = wk >> 1;
    const int gcol0 = yg * 128;
    const int rowbase = rb * 128;

    const int l = tid & 63, w = tid >> 6;
    const int lr = l & 15, lg = l >> 4;
    const int rowg = w >> 1;          // 2 row groups x 64 rows
    const int colb = (w & 1) * 64;    // 2 col groups x 64 cols

    const size_t chstride = (size_t)mTot * 64;   // bytes per K32 chunk

    // W phase p -> wbuf (p&1): 16KB contiguous (4x 1KB instr/wave)
    auto stageW = [&](int p) {
        char* wb = lds + ((p & 1) << 14);
        const char* src = (const char*)Wp + (size_t)p * 32768 + (size_t)gcol0 * 128;
#pragma unroll
        for (int i = 0; i < 4; ++i) {
            int o = w * 4096 + i * 1024;
            dma16(src + o + l * 16, wb + o + l * 16);
        }
    };
    // A phase p (chunks 2p,2p+1) -> registers; fragment = 1KB coalesced
    const unsigned aoff = (unsigned)(rowbase + rowg * 64 + lr) * 64 + (lg << 4);
    auto loadA = [&](int p, short8 (&a)[4][2]) {
        const char* base = (NK == 8 && p >= 4) ? (const char*)a1p : (const char*)a0p;
#pragma unroll
        for (int m = 0; m < 4; ++m)
#pragma unroll
            for (int sub = 0; sub < 2; ++sub) {
                const int c = (2 * p + sub) & 7;
                a[m][sub] = *(const short8*)(base + (size_t)c * chstride +
                                             aoff + (unsigned)(m * 16) * 64);
            }
    };

    short8 aA[4][2], aB[4][2];
    // prologue: A0 -> aA, W0 -> buf0
    loadA(0, aA);
    stageW(0);

    f32x4 acc[4][4];
#pragma unroll
    for (int m = 0; m < 4; ++m)
#pragma unroll
        for (int j = 0; j < 4; ++j) acc[m][j] = (f32x4){0.f, 0.f, 0.f, 0.f};

#pragma unroll
    for (int kk = 0; kk < NK; ++kk) {
        WAIT_VM(0);
        __builtin_amdgcn_s_barrier();
        SOFT_FENCE;

        if (kk + 1 < NK) {
            if (kk & 1) loadA(kk + 1, aA); else loadA(kk + 1, aB);
            stageW(kk + 1);
        }

        const short8(*cur)[2] = (kk & 1) ? aB : aA;
        char* wbuf = lds + ((kk & 1) << 14);
#pragma unroll
        for (int sub = 0; sub < 2; ++sub) {
            const int kq0 = (sub << 6) | (lg << 4);
#pragma unroll
            for (int j = 0; j < 4; ++j) {
                const int col = colb + j * 16 + lr;
                const short8 wf = *(const short8*)(
                    wbuf + (col << 7) + (kq0 ^ ((lr & 7) << 4)));
#pragma unroll
                for (int m = 0; m < 4; ++m)
                    acc[m][j] = __builtin_amdgcn_mfma_f32_16x16x32_bf16(wf, cur[m][sub], acc[m][j], 0, 0, 0);
            }
        }
        SOFT_FENCE;
    }

    // epilogue (swapped layout): lane holds 4 consecutive cols
#pragma unroll
    for (int m = 0; m < 4; ++m) {
        const int row = rowbase + rowg * 64 + m * 16 + lr;
#pragma unroll
        for (int j = 0; j < 4; ++j) {
            const int gcol = gcol0 + colb + j * 16 + lg * 4;
            const float4 bv = *(const float4*)(bias + gcol);
            float o0 = fmaxf(acc[m][j][0] + bv.x, 0.f);
            float o1 = fmaxf(acc[m][j][1] + bv.y, 0.f);
            float o2 = fmaxf(acc[m][j][2] + bv.z, 0.f);
            float o3 = fmaxf(acc[m][j][3] + bv.w, 0.f);
            if constexpr (sizeof(TOUT) == 4) {
                float4 o = {o0, o1, o2, o3};
                *(float4*)((float*)out + (size_t)row * 256 + gcol) = o;
            } else {
                union { unsigned short u[4]; uint2 v; } pk;
                pk.u[0] = f2bf(o0); pk.u[1] = f2bf(o1);
                pk.u[2] = f2bf(o2); pk.u[3] = f2bf(o3);
                unsigned short* hp = (unsigned short*)out +
                    (size_t)(gcol >> 5) * ((size_t)mTot * 32) +
                    (size_t)row * 32 + (gcol & 31);
                *(uint2*)hp = pk.v;
            }
        }
    }
}

// ---- v3 fallback (small ws): fused gather, weights all-K in LDS ----
template <int C, typename TIN, typename TOUT>
__global__ __launch_bounds__(512, 2) void sage_v3(
    const TIN* __restrict__ hin, const int* __restrict__ nbr,
    const unsigned short* __restrict__ Wt, const float* __restrict__ bias,
    TOUT* __restrict__ out) {
    constexpr int K2 = 2 * C;
    constexpr int ROWB = K2 * 2;
    constexpr int LCOLS = 131072 / ROWB;
    constexpr int CG = LCOLS / 128;
    constexpr int RG = 8 / CG;
    extern __shared__ char Bs[];

    const int tid = threadIdx.x;
    const int gcol0 = blockIdx.y * LCOLS;
    {
        const char* src = (const char*)(Wt + (size_t)gcol0 * K2);
#pragma unroll
        for (int i = 0; i < 16; ++i) {
            int byt = (i * 512 + tid) * 16;
            uint4 v = *(const uint4*)(src + byt);
            int c = byt / ROWB;
            *(uint4*)(Bs + (byt ^ ((c & 7) << 4))) = v;
        }
    }
    __syncthreads();

    const int l = tid & 63;
    const int w = tid >> 6;
    const int rowg = w / CG;
    const int colb = (w % CG) * 128;
    const int lr = l & 15, lg = l >> 4;

    const int rowbase = blockIdx.x * (RG * 64) + rowg * 64;
    const int bb = rowbase / NNODES;
    const int n0 = rowbase - bb * NNODES;
    const size_t bbase = (size_t)bb * NNODES;

    unsigned soff[4], noff[4][4];
#pragma unroll
    for (int m = 0; m < 4; ++m) {
        int r = m * 16 + lr;
        soff[m] = (unsigned)(((rowbase + r) * (size_t)C + lg * 8) * sizeof(TIN));
        int4 nb = *(const int4*)(nbr + (size_t)(n0 + r) * 4);
        noff[m][0] = (unsigned)(((bbase + nb.x) * C + lg * 8) * sizeof(TIN));
        noff[m][1] = (unsigned)(((bbase + nb.y) * C + lg * 8) * sizeof(TIN));
        noff[m][2] = (unsigned)(((bbase + nb.z) * C + lg * 8) * sizeof(TIN));
        noff[m][3] = (unsigned)(((bbase + nb.w) * C + lg * 8) * sizeof(TIN));
    }
    const char* hb = (const char*)hin;

    f32x4 acc[4][8];
#pragma unroll
    for (int m = 0; m < 4; ++m)
#pragma unroll
        for (int j = 0; j < 8; ++j) acc[m][j] = (f32x4){0.f, 0.f, 0.f, 0.f};

#pragma unroll
    for (int kk = 0; kk < K2 / 32; ++kk) {
        const int k0 = kk * 32;
        short8 a[4];
        if (k0 < C) {
            const unsigned kb = k0 * sizeof(TIN);
#pragma unroll
            for (int m = 0; m < 4; ++m)
                a[m] = frag_self((const TIN*)(hb + soff[m] + kb));
        } else {
            const unsigned kb = (k0 - C) * sizeof(TIN);
#pragma unroll
            for (int m = 0; m < 4; ++m)
                a[m] = frag_mean4((const TIN*)(hb + noff[m][0] + kb),
                                  (const TIN*)(hb + noff[m][1] + kb),
                                  (const TIN*)(hb + noff[m][2] + kb),
                                  (const TIN*)(hb + noff[m][3] + kb));
        }
#pragma unroll
        for (int j = 0; j < 8; ++j) {
            const int c = colb + j * 16 + lr;
            const short8 bf = *(const short8*)(
                Bs + ((c * ROWB + (k0 + lg * 8) * 2) ^ ((l & 7) << 4)));
#pragma unroll
            for (int m = 0; m < 4; ++m)
                acc[m][j] = __builtin_amdgcn_mfma_f32_16x16x32_bf16(a[m], bf, acc[m][j], 0, 0, 0);
        }
    }

#pragma unroll
    for (int j = 0; j < 8; ++j) {
        const int gcol = gcol0 + colb + j * 16 + lr;
        const float bv = bias[gcol];
#pragma unroll
        for (int m = 0; m < 4; ++m) {
#pragma unroll
            for (int r = 0; r < 4; ++r) {
                const int row = rowbase + m * 16 + lg * 4 + r;
                storev(out + (size_t)row * DOUT + gcol, fmaxf(acc[m][j][r] + bv, 0.f));
            }
        }
    }
}

extern "C" void kernel_launch(void* const* d_in, const int* in_sizes, int n_in,
                              void* d_out, int out_size, void* d_ws, size_t ws_size,
                              hipStream_t stream) {
    const float* x = (const float*)d_in[0];
    const int* nbr = (const int*)d_in[1];
    const float* Ws1 = (const float*)d_in[2];
    const float* Wn1 = (const float*)d_in[3];
    const float* b1 = (const float*)d_in[4];
    const float* Ws2 = (const float*)d_in[5];
    const float* Wn2 = (const float*)d_in[6];
    const float* b2 = (const float*)d_in[7];
    float* out = (float*)d_out;

    const int B = in_sizes[0] / (NNODES * 128);  // 4
    const int M = B * NNODES;                    // 221184

    char* ws = (char*)d_ws;
    const size_t h1_bytes = (size_t)M * DOUT * 2;
    const size_t hm_bytes = (size_t)M * DOUT * 2;  // xm_pm for L1, then hm_pm for L2
    const size_t need = h1_bytes + hm_bytes + 131072 + 262144;

    if (ws_size >= need) {
        unsigned short* h1 = (unsigned short*)ws;                       // phase-major
        unsigned short* xm = (unsigned short*)(ws + h1_bytes);          // pm; reused hm
        unsigned short* W1p = (unsigned short*)(ws + h1_bytes + hm_bytes);
        unsigned short* W2p = W1p + 256 * 256;

        build_wt_pm<<<256, 256, 0, stream>>>(Ws1, Wn1, W1p, 128);
        build_wt_pm<<<512, 256, 0, stream>>>(Ws2, Wn2, W2p, 256);

        hipFuncSetAttribute((const void*)sage_v16<4, unsigned short>,
                            hipFuncAttributeMaxDynamicSharedMemorySize, 32768);
        hipFuncSetAttribute((const void*)sage_v16<8, float>,
                            hipFuncAttributeMaxDynamicSharedMemorySize, 32768);

        const int nwg = (M / 128) * 2;  // 3456, divisible by 8

        // layer 1: xm_pm = [bf16(x) | mean4(x)] phase-major; K2=256 GEMM (4 phases)
        mean_xb_pm<<<M / 16, 256, 0, stream>>>(x, nbr, xm, M);
        sage_v16<4, unsigned short>
            <<<nwg, 256, 32768, stream>>>(xm, xm, W1p, b1, h1, nwg, M);
        // layer 2: hm_pm overwrites xm; K2=512 GEMM (8 phases, A = h1_pm then hm_pm)
        mean_pass_pm<<<M / 8, 256, 0, stream>>>(h1, nbr, xm, M);
        sage_v16<8, float>
            <<<nwg, 256, 32768, stream>>>(h1, xm, W2p, b2, out, nwg, M);
    } else {
        unsigned short* h1 = (unsigned short*)ws;
        unsigned short* Wt1 = (unsigned short*)(ws + h1_bytes);
        unsigned short* Wt2 = Wt1 + 256 * 256;

        build_wt<<<256, 256, 0, stream>>>(Ws1, Wn1, Wt1, 128);
        build_wt<<<512, 256, 0, stream>>>(Ws2, Wn2, Wt2, 256);

        hipFuncSetAttribute((const void*)sage_v3<128, float, unsigned short>,
                            hipFuncAttributeMaxDynamicSharedMemorySize, 131072);
        hipFuncSetAttribute((const void*)sage_v3<256, unsigned short, float>,
                            hipFuncAttributeMaxDynamicSharedMemorySize, 131072);

        sage_v3<128, float, unsigned short>
            <<<dim3(M / 256, 1), 512, 131072, stream>>>(x, nbr, Wt1, b1, h1);
        sage_v3<256, unsigned short, float>
            <<<dim3(M / 512, 2), 512, 131072, stream>>>(h1, nbr, Wt2, b2, out);
    }
}

// Round 18
// 320.761 us; speedup vs baseline: 1.1077x; 1.1077x over previous
//
#include <hip/hip_runtime.h>
#include <stdint.h>

typedef __attribute__((ext_vector_type(8))) short short8;
typedef __attribute__((ext_vector_type(4))) float f32x4;

#define NNODES 55296
#define DOUT 256

#define WAIT_VM(N) asm volatile("s_waitcnt vmcnt(" #N ")" ::: "memory")
#define SOFT_FENCE asm volatile("" ::: "memory")

__device__ __forceinline__ float bf2f(unsigned short h) {
    union { unsigned u; float f; } x; x.u = ((unsigned)h) << 16; return x.f;
}
__device__ __forceinline__ unsigned short f2bf(float f) {
    union { float f; unsigned u; } x; x.f = f;
    return (unsigned short)((x.u + 0x7fffu + ((x.u >> 16) & 1u)) >> 16);
}

__device__ __forceinline__ void storev(float* p, float v) { *p = v; }
__device__ __forceinline__ void storev(unsigned short* p, float v) { *p = f2bf(v); }

__device__ __forceinline__ void dma16(const void* g, void* l) {
    __builtin_amdgcn_global_load_lds(
        reinterpret_cast<const unsigned int __attribute__((address_space(1)))*>((uintptr_t)g),
        reinterpret_cast<unsigned int __attribute__((address_space(3)))*>((uintptr_t)l),
        16, 0, 0);
}

// ---- fragment helpers (v3 fallback + mean kernels) ----
__device__ __forceinline__ short8 frag_self(const float* p) {
    float4 a = *(const float4*)p, b = *(const float4*)(p + 4);
    union { short8 s; unsigned short u[8]; } r;
    r.u[0] = f2bf(a.x); r.u[1] = f2bf(a.y); r.u[2] = f2bf(a.z); r.u[3] = f2bf(a.w);
    r.u[4] = f2bf(b.x); r.u[5] = f2bf(b.y); r.u[6] = f2bf(b.z); r.u[7] = f2bf(b.w);
    return r.s;
}
__device__ __forceinline__ short8 frag_self(const unsigned short* p) {
    return *(const short8*)p;
}
__device__ __forceinline__ void acc8(const float* p, float* o) {
    float4 a = *(const float4*)p, b = *(const float4*)(p + 4);
    o[0] += a.x; o[1] += a.y; o[2] += a.z; o[3] += a.w;
    o[4] += b.x; o[5] += b.y; o[6] += b.z; o[7] += b.w;
}
__device__ __forceinline__ void acc8(const unsigned short* p, float* o) {
    uint4 v = *(const uint4*)p;
    const unsigned short* u = (const unsigned short*)&v;
#pragma unroll
    for (int i = 0; i < 8; ++i) o[i] += bf2f(u[i]);
}
template <typename TIN>
__device__ __forceinline__ short8 frag_mean4(const TIN* p0, const TIN* p1,
                                             const TIN* p2, const TIN* p3) {
    float s[8] = {0.f, 0.f, 0.f, 0.f, 0.f, 0.f, 0.f, 0.f};
    acc8(p0, s); acc8(p1, s); acc8(p2, s); acc8(p3, s);
    union { short8 s8; unsigned short u[8]; } r;
#pragma unroll
    for (int i = 0; i < 8; ++i) r.u[i] = f2bf(s[i] * 0.25f);
    return r.s8;
}

// ---- old Wt (d-major) for v3 fallback ----
__global__ void build_wt(const float* __restrict__ Ws,
                         const float* __restrict__ Wn,
                         unsigned short* __restrict__ Wt, int C) {
    int K2 = 2 * C;
    int idx = blockIdx.x * 256 + threadIdx.x;
    if (idx >= 256 * K2) return;
    int d = idx / K2;
    int k = idx - d * K2;
    float v = (k < C) ? Ws[(size_t)k * DOUT + d] : Wn[(size_t)(k - C) * DOUT + d];
    Wt[idx] = f2bf(v);
}

// ---- pair-major pre-swizzled W: Wp[q][col 256][128B], byte kq ^ ((col&7)<<4) ----
__global__ void build_wt_pm(const float* __restrict__ Ws,
                            const float* __restrict__ Wn,
                            unsigned short* __restrict__ Wp, int C) {
    int K2 = 2 * C;
    int idx = blockIdx.x * 256 + threadIdx.x;
    if (idx >= 256 * K2) return;
    int d = idx / K2;
    int k = idx - d * K2;
    float v = (k < C) ? Ws[(size_t)k * DOUT + d] : Wn[(size_t)(k - C) * DOUT + d];
    int q = k >> 6;
    int kqb = (k & 63) * 2;
    int byte = q * 32768 + d * 128 + (kqb ^ ((d & 7) << 4));
    Wp[byte >> 1] = f2bf(v);
}

// ---- layer-1 prep (phase-major): xm_pm[c][M][32 elems]; c<4 self, c>=4 mean ----
__global__ __launch_bounds__(256) void mean_xb_pm(const float* __restrict__ x,
                                                  const int* __restrict__ nbr,
                                                  unsigned short* __restrict__ xm,
                                                  int mTot) {
    const int idx = blockIdx.x * 256 + threadIdx.x;
    const int node = idx >> 4;
    const int ch = (idx & 15) * 8;         // 0..120
    const int b = node / NNODES;
    const int n = node - b * NNODES;
    const size_t bbase = (size_t)b * NNODES;
    const int4 nb = *(const int4*)(nbr + (size_t)n * 4);
    const float* ps = x + (size_t)node * 128 + ch;
    union { uint4 v; unsigned short u[8]; } rs, rm;
    float4 a0 = *(const float4*)ps, a1 = *(const float4*)(ps + 4);
    rs.u[0] = f2bf(a0.x); rs.u[1] = f2bf(a0.y); rs.u[2] = f2bf(a0.z); rs.u[3] = f2bf(a0.w);
    rs.u[4] = f2bf(a1.x); rs.u[5] = f2bf(a1.y); rs.u[6] = f2bf(a1.z); rs.u[7] = f2bf(a1.w);
    float s[8] = {0.f, 0.f, 0.f, 0.f, 0.f, 0.f, 0.f, 0.f};
    acc8(x + (bbase + nb.x) * 128 + ch, s);
    acc8(x + (bbase + nb.y) * 128 + ch, s);
    acc8(x + (bbase + nb.z) * 128 + ch, s);
    acc8(x + (bbase + nb.w) * 128 + ch, s);
#pragma unroll
    for (int i = 0; i < 8; ++i) rm.u[i] = f2bf(s[i] * 0.25f);
    const size_t cs = (size_t)mTot * 32;
    *(uint4*)(xm + (size_t)(ch >> 5) * cs + (size_t)node * 32 + (ch & 31)) = rs.v;
    *(uint4*)(xm + (size_t)(4 + (ch >> 5)) * cs + (size_t)node * 32 + (ch & 31)) = rm.v;
}

// ---- hm_pm = mean4(h1_pm), coalesced: blockIdx.y = plane, sub cycles fastest
// -> every load/store instruction is 64 lanes x 16B fully contiguous ----
__global__ __launch_bounds__(256) void mean_pass_pm2(const unsigned short* __restrict__ h1,
                                                     const int* __restrict__ nbr,
                                                     unsigned short* __restrict__ hm,
                                                     int mTot) {
    const int idx = blockIdx.x * 256 + threadIdx.x;   // node*4 + sub
    const int sub = idx & 3;
    const int node = idx >> 2;
    const int plane = blockIdx.y;                     // 0..7
    const int b = node / NNODES;
    const int n = node - b * NNODES;
    const size_t bbase = (size_t)b * NNODES;
    const int4 nb = *(const int4*)(nbr + (size_t)n * 4);
    const size_t co = (size_t)plane * ((size_t)mTot * 32) + sub * 8;
    float s[8] = {0.f, 0.f, 0.f, 0.f, 0.f, 0.f, 0.f, 0.f};
    acc8(h1 + co + (bbase + nb.x) * 32, s);
    acc8(h1 + co + (bbase + nb.y) * 32, s);
    acc8(h1 + co + (bbase + nb.z) * 32, s);
    acc8(h1 + co + (bbase + nb.w) * 32, s);
    union { uint4 v; unsigned short u[8]; } r;
#pragma unroll
    for (int i = 0; i < 8; ++i) r.u[i] = f2bf(s[i] * 0.25f);
    *(uint4*)(hm + co + (size_t)node * 32) = r.v;
}

// ============================================================================
// v15 (round-16 proven best): K=64 phases. NK = K2/64.
//   W: dbuf 2x16KB, staged 1 phase ahead (contiguous 16KB).
//   A: ring 3x16KB, staged 2 phases ahead (2x 8KB contiguous).
//   Uniform vmcnt(4); 0 at end. LDS 80KB -> 2 blocks/CU. Tile 128x128,
//   4 waves; XCD-chunked bijective swizzle; MFMA swapped (wf, af).
// ============================================================================
template <int NK, typename TOUT>
__global__ __launch_bounds__(256) void sage_v15(
    const unsigned short* __restrict__ a0p,   // phase-major A chunks [0,8)
    const unsigned short* __restrict__ a1p,   // phase-major A chunks [8,16)
    const unsigned short* __restrict__ Wp,    // [NK q][256 col][128B] pre-swz
    const float* __restrict__ bias,           // [256]
    TOUT* __restrict__ out,                   // h1_pm (bf16) or [M][256] f32
    int nwg, int mTot) {
    extern __shared__ char lds[];
    const int tid = threadIdx.x;
    const int bid = blockIdx.x;
    const int wk = (bid & 7) * (nwg >> 3) + (bid >> 3);  // bijective (nwg%8==0)
    const int yg = wk & 1;
    const int rb = wk >> 1;
    const int gcol0 = yg * 128;
    const int rowbase = rb * 128;

    const int l = tid & 63, w = tid >> 6;
    const int lr = l & 15, lg = l >> 4;
    const int rowg = w >> 1;          // 2 row groups x 64 rows
    const int colb = (w & 1) * 64;    // 2 col groups x 64 cols

    const size_t chstride = (size_t)mTot * 64;   // bytes per K32 chunk

    auto stageW = [&](int p) {
        char* wb = lds + ((p & 1) << 14);
        const char* src = (const char*)Wp + (size_t)p * 32768 + (size_t)gcol0 * 128;
#pragma unroll
        for (int i = 0; i < 4; ++i) {
            int o = w * 4096 + i * 1024;
            dma16(src + o + l * 16, wb + o + l * 16);
        }
    };
    auto issueA = [&](int p) {
        const char* base = (p >= 4) ? (const char*)a1p : (const char*)a0p;
        const char* src = base + (size_t)((2 * p) & 7) * chstride + (size_t)rowbase * 64;
        char* ring = lds + 32768 + (p % 3) * 16384;
#pragma unroll
        for (int s = 0; s < 2; ++s) {
            const char* cs_ = src + (size_t)s * chstride;
            char* dst = ring + s * 8192;
#pragma unroll
            for (int i = 0; i < 2; ++i) {
                int o = w * 2048 + i * 1024;
                dma16(cs_ + o + l * 16, dst + o + l * 16);
            }
        }
    };

    stageW(0); issueA(0); issueA(1);

    f32x4 acc[4][4];
#pragma unroll
    for (int m = 0; m < 4; ++m)
#pragma unroll
        for (int j = 0; j < 4; ++j) acc[m][j] = (f32x4){0.f, 0.f, 0.f, 0.f};

#pragma unroll
    for (int kk = 0; kk < NK; ++kk) {
        if (kk == NK - 1) { WAIT_VM(0); } else { WAIT_VM(4); }
        __builtin_amdgcn_s_barrier();
        SOFT_FENCE;

        if (kk + 1 < NK) stageW(kk + 1);
        if (kk + 2 < NK) issueA(kk + 2);

        const int ringo = 32768 + (kk % 3) * 16384;
        char* wbuf = lds + ((kk & 1) << 14);
#pragma unroll
        for (int sub = 0; sub < 2; ++sub) {
            short8 af[4];
#pragma unroll
            for (int m = 0; m < 4; ++m)
                af[m] = *(const short8*)(lds + ringo + sub * 8192 +
                                         ((rowg * 4 + m) * 16 + lr) * 64 + lg * 16);
            const int kq0 = (sub << 6) | (lg << 4);
#pragma unroll
            for (int j = 0; j < 4; ++j) {
                const int col = colb + j * 16 + lr;
                const short8 wf = *(const short8*)(
                    wbuf + (col << 7) + (kq0 ^ ((lr & 7) << 4)));
#pragma unroll
                for (int m = 0; m < 4; ++m)
                    acc[m][j] = __builtin_amdgcn_mfma_f32_16x16x32_bf16(wf, af[m], acc[m][j], 0, 0, 0);
            }
        }
        SOFT_FENCE;
    }

    // epilogue (swapped layout): lane holds 4 consecutive cols
#pragma unroll
    for (int m = 0; m < 4; ++m) {
        const int row = rowbase + rowg * 64 + m * 16 + lr;
#pragma unroll
        for (int j = 0; j < 4; ++j) {
            const int gcol = gcol0 + colb + j * 16 + lg * 4;
            const float4 bv = *(const float4*)(bias + gcol);
            float o0 = fmaxf(acc[m][j][0] + bv.x, 0.f);
            float o1 = fmaxf(acc[m][j][1] + bv.y, 0.f);
            float o2 = fmaxf(acc[m][j][2] + bv.z, 0.f);
            float o3 = fmaxf(acc[m][j][3] + bv.w, 0.f);
            if constexpr (sizeof(TOUT) == 4) {
                float4 o = {o0, o1, o2, o3};
                *(float4*)((float*)out + (size_t)row * 256 + gcol) = o;
            } else {
                union { unsigned short u[4]; uint2 v; } pk;
                pk.u[0] = f2bf(o0); pk.u[1] = f2bf(o1);
                pk.u[2] = f2bf(o2); pk.u[3] = f2bf(o3);
                unsigned short* hp = (unsigned short*)out +
                    (size_t)(gcol >> 5) * ((size_t)mTot * 32) +
                    (size_t)row * 32 + (gcol & 31);
                *(uint2*)hp = pk.v;
            }
        }
    }
}

// ---- v3 fallback (small ws): fused gather, weights all-K in LDS ----
template <int C, typename TIN, typename TOUT>
__global__ __launch_bounds__(512, 2) void sage_v3(
    const TIN* __restrict__ hin, const int* __restrict__ nbr,
    const unsigned short* __restrict__ Wt, const float* __restrict__ bias,
    TOUT* __restrict__ out) {
    constexpr int K2 = 2 * C;
    constexpr int ROWB = K2 * 2;
    constexpr int LCOLS = 131072 / ROWB;
    constexpr int CG = LCOLS / 128;
    constexpr int RG = 8 / CG;
    extern __shared__ char Bs[];

    const int tid = threadIdx.x;
    const int gcol0 = blockIdx.y * LCOLS;
    {
        const char* src = (const char*)(Wt + (size_t)gcol0 * K2);
#pragma unroll
        for (int i = 0; i < 16; ++i) {
            int byt = (i * 512 + tid) * 16;
            uint4 v = *(const uint4*)(src + byt);
            int c = byt / ROWB;
            *(uint4*)(Bs + (byt ^ ((c & 7) << 4))) = v;
        }
    }
    __syncthreads();

    const int l = tid & 63;
    const int w = tid >> 6;
    const int rowg = w / CG;
    const int colb = (w % CG) * 128;
    const int lr = l & 15, lg = l >> 4;

    const int rowbase = blockIdx.x * (RG * 64) + rowg * 64;
    const int bb = rowbase / NNODES;
    const int n0 = rowbase - bb * NNODES;
    const size_t bbase = (size_t)bb * NNODES;

    unsigned soff[4], noff[4][4];
#pragma unroll
    for (int m = 0; m < 4; ++m) {
        int r = m * 16 + lr;
        soff[m] = (unsigned)(((rowbase + r) * (size_t)C + lg * 8) * sizeof(TIN));
        int4 nb = *(const int4*)(nbr + (size_t)(n0 + r) * 4);
        noff[m][0] = (unsigned)(((bbase + nb.x) * C + lg * 8) * sizeof(TIN));
        noff[m][1] = (unsigned)(((bbase + nb.y) * C + lg * 8) * sizeof(TIN));
        noff[m][2] = (unsigned)(((bbase + nb.z) * C + lg * 8) * sizeof(TIN));
        noff[m][3] = (unsigned)(((bbase + nb.w) * C + lg * 8) * sizeof(TIN));
    }
    const char* hb = (const char*)hin;

    f32x4 acc[4][8];
#pragma unroll
    for (int m = 0; m < 4; ++m)
#pragma unroll
        for (int j = 0; j < 8; ++j) acc[m][j] = (f32x4){0.f, 0.f, 0.f, 0.f};

#pragma unroll
    for (int kk = 0; kk < K2 / 32; ++kk) {
        const int k0 = kk * 32;
        short8 a[4];
        if (k0 < C) {
            const unsigned kb = k0 * sizeof(TIN);
#pragma unroll
            for (int m = 0; m < 4; ++m)
                a[m] = frag_self((const TIN*)(hb + soff[m] + kb));
        } else {
            const unsigned kb = (k0 - C) * sizeof(TIN);
#pragma unroll
            for (int m = 0; m < 4; ++m)
                a[m] = frag_mean4((const TIN*)(hb + noff[m][0] + kb),
                                  (const TIN*)(hb + noff[m][1] + kb),
                                  (const TIN*)(hb + noff[m][2] + kb),
                                  (const TIN*)(hb + noff[m][3] + kb));
        }
#pragma unroll
        for (int j = 0; j < 8; ++j) {
            const int c = colb + j * 16 + lr;
            const short8 bf = *(const short8*)(
                Bs + ((c * ROWB + (k0 + lg * 8) * 2) ^ ((l & 7) << 4)));
#pragma unroll
            for (int m = 0; m < 4; ++m)
                acc[m][j] = __builtin_amdgcn_mfma_f32_16x16x32_bf16(a[m], bf, acc[m][j], 0, 0, 0);
        }
    }

#pragma unroll
    for (int j = 0; j < 8; ++j) {
        const int gcol = gcol0 + colb + j * 16 + lr;
        const float bv = bias[gcol];
#pragma unroll
        for (int m = 0; m < 4; ++m) {
#pragma unroll
            for (int r = 0; r < 4; ++r) {
                const int row = rowbase + m * 16 + lg * 4 + r;
                storev(out + (size_t)row * DOUT + gcol, fmaxf(acc[m][j][r] + bv, 0.f));
            }
        }
    }
}

extern "C" void kernel_launch(void* const* d_in, const int* in_sizes, int n_in,
                              void* d_out, int out_size, void* d_ws, size_t ws_size,
                              hipStream_t stream) {
    const float* x = (const float*)d_in[0];
    const int* nbr = (const int*)d_in[1];
    const float* Ws1 = (const float*)d_in[2];
    const float* Wn1 = (const float*)d_in[3];
    const float* b1 = (const float*)d_in[4];
    const float* Ws2 = (const float*)d_in[5];
    const float* Wn2 = (const float*)d_in[6];
    const float* b2 = (const float*)d_in[7];
    float* out = (float*)d_out;

    const int B = in_sizes[0] / (NNODES * 128);  // 4
    const int M = B * NNODES;                    // 221184

    char* ws = (char*)d_ws;
    const size_t h1_bytes = (size_t)M * DOUT * 2;
    const size_t hm_bytes = (size_t)M * DOUT * 2;  // xm_pm for L1, then hm_pm for L2
    const size_t need = h1_bytes + hm_bytes + 131072 + 262144;

    if (ws_size >= need) {
        unsigned short* h1 = (unsigned short*)ws;                       // phase-major
        unsigned short* xm = (unsigned short*)(ws + h1_bytes);          // pm; reused hm
        unsigned short* W1p = (unsigned short*)(ws + h1_bytes + hm_bytes);
        unsigned short* W2p = W1p + 256 * 256;

        build_wt_pm<<<256, 256, 0, stream>>>(Ws1, Wn1, W1p, 128);
        build_wt_pm<<<512, 256, 0, stream>>>(Ws2, Wn2, W2p, 256);

        hipFuncSetAttribute((const void*)sage_v15<4, unsigned short>,
                            hipFuncAttributeMaxDynamicSharedMemorySize, 81920);
        hipFuncSetAttribute((const void*)sage_v15<8, float>,
                            hipFuncAttributeMaxDynamicSharedMemorySize, 81920);

        const int nwg = (M / 128) * 2;  // 3456, divisible by 8

        // layer 1: xm_pm = [bf16(x) | mean4(x)] phase-major; K2=256 GEMM (4 phases)
        mean_xb_pm<<<M / 16, 256, 0, stream>>>(x, nbr, xm, M);
        sage_v15<4, unsigned short>
            <<<nwg, 256, 81920, stream>>>(xm, xm, W1p, b1, h1, nwg, M);
        // layer 2: hm_pm overwrites xm; K2=512 GEMM (8 phases, A = h1_pm then hm_pm)
        mean_pass_pm2<<<dim3(M / 64, 8), 256, 0, stream>>>(h1, nbr, xm, M);
        sage_v15<8, float>
            <<<nwg, 256, 81920, stream>>>(h1, xm, W2p, b2, out, nwg, M);
    } else {
        unsigned short* h1 = (unsigned short*)ws;
        unsigned short* Wt1 = (unsigned short*)(ws + h1_bytes);
        unsigned short* Wt2 = Wt1 + 256 * 256;

        build_wt<<<256, 256, 0, stream>>>(Ws1, Wn1, Wt1, 128);
        build_wt<<<512, 256, 0, stream>>>(Ws2, Wn2, Wt2, 256);

        hipFuncSetAttribute((const void*)sage_v3<128, float, unsigned short>,
                            hipFuncAttributeMaxDynamicSharedMemorySize, 131072);
        hipFuncSetAttribute((const void*)sage_v3<256, unsigned short, float>,
                            hipFuncAttributeMaxDynamicSharedMemorySize, 131072);

        sage_v3<128, float, unsigned short>
            <<<dim3(M / 256, 1), 512, 131072, stream>>>(x, nbr, Wt1, b1, h1);
        sage_v3<256, unsigned short, float>
            <<<dim3(M / 512, 2), 512, 131072, stream>>>(h1, nbr, Wt2, b2, out);
    }
}

// Round 19
// 316.961 us; speedup vs baseline: 1.1209x; 1.0120x over previous
//
#include <hip/hip_runtime.h>
#include <stdint.h>

typedef __attribute__((ext_vector_type(8))) short short8;
typedef __attribute__((ext_vector_type(4))) float f32x4;

#define NNODES 55296
#define DOUT 256

#define WAIT_VM(N) asm volatile("s_waitcnt vmcnt(" #N ")" ::: "memory")
#define SOFT_FENCE asm volatile("" ::: "memory")

__device__ __forceinline__ float bf2f(unsigned short h) {
    union { unsigned u; float f; } x; x.u = ((unsigned)h) << 16; return x.f;
}
__device__ __forceinline__ unsigned short f2bf(float f) {
    union { float f; unsigned u; } x; x.f = f;
    return (unsigned short)((x.u + 0x7fffu + ((x.u >> 16) & 1u)) >> 16);
}

__device__ __forceinline__ void storev(float* p, float v) { *p = v; }
__device__ __forceinline__ void storev(unsigned short* p, float v) { *p = f2bf(v); }

__device__ __forceinline__ void dma16(const void* g, void* l) {
    __builtin_amdgcn_global_load_lds(
        reinterpret_cast<const unsigned int __attribute__((address_space(1)))*>((uintptr_t)g),
        reinterpret_cast<unsigned int __attribute__((address_space(3)))*>((uintptr_t)l),
        16, 0, 0);
}

// ---- fragment helpers (v3 fallback + mean kernels) ----
__device__ __forceinline__ short8 frag_self(const float* p) {
    float4 a = *(const float4*)p, b = *(const float4*)(p + 4);
    union { short8 s; unsigned short u[8]; } r;
    r.u[0] = f2bf(a.x); r.u[1] = f2bf(a.y); r.u[2] = f2bf(a.z); r.u[3] = f2bf(a.w);
    r.u[4] = f2bf(b.x); r.u[5] = f2bf(b.y); r.u[6] = f2bf(b.z); r.u[7] = f2bf(b.w);
    return r.s;
}
__device__ __forceinline__ short8 frag_self(const unsigned short* p) {
    return *(const short8*)p;
}
__device__ __forceinline__ void acc8(const float* p, float* o) {
    float4 a = *(const float4*)p, b = *(const float4*)(p + 4);
    o[0] += a.x; o[1] += a.y; o[2] += a.z; o[3] += a.w;
    o[4] += b.x; o[5] += b.y; o[6] += b.z; o[7] += b.w;
}
__device__ __forceinline__ void acc8(const unsigned short* p, float* o) {
    uint4 v = *(const uint4*)p;
    const unsigned short* u = (const unsigned short*)&v;
#pragma unroll
    for (int i = 0; i < 8; ++i) o[i] += bf2f(u[i]);
}
template <typename TIN>
__device__ __forceinline__ short8 frag_mean4(const TIN* p0, const TIN* p1,
                                             const TIN* p2, const TIN* p3) {
    float s[8] = {0.f, 0.f, 0.f, 0.f, 0.f, 0.f, 0.f, 0.f};
    acc8(p0, s); acc8(p1, s); acc8(p2, s); acc8(p3, s);
    union { short8 s8; unsigned short u[8]; } r;
#pragma unroll
    for (int i = 0; i < 8; ++i) r.u[i] = f2bf(s[i] * 0.25f);
    return r.s8;
}

// ---- old Wt (d-major) for v3 fallback ----
__global__ void build_wt(const float* __restrict__ Ws,
                         const float* __restrict__ Wn,
                         unsigned short* __restrict__ Wt, int C) {
    int K2 = 2 * C;
    int idx = blockIdx.x * 256 + threadIdx.x;
    if (idx >= 256 * K2) return;
    int d = idx / K2;
    int k = idx - d * K2;
    float v = (k < C) ? Ws[(size_t)k * DOUT + d] : Wn[(size_t)(k - C) * DOUT + d];
    Wt[idx] = f2bf(v);
}

// ---- pair-major pre-swizzled W: Wp[q][col 256][128B], byte kq ^ ((col&7)<<4) ----
__global__ void build_wt_pm(const float* __restrict__ Ws,
                            const float* __restrict__ Wn,
                            unsigned short* __restrict__ Wp, int C) {
    int K2 = 2 * C;
    int idx = blockIdx.x * 256 + threadIdx.x;
    if (idx >= 256 * K2) return;
    int d = idx / K2;
    int k = idx - d * K2;
    float v = (k < C) ? Ws[(size_t)k * DOUT + d] : Wn[(size_t)(k - C) * DOUT + d];
    int q = k >> 6;
    int kqb = (k & 63) * 2;
    int byte = q * 32768 + d * 128 + (kqb ^ ((d & 7) << 4));
    Wp[byte >> 1] = f2bf(v);
}

// ---- layer-1 prep (phase-major): xm_pm[c][M][32 elems]; c<4 self, c>=4 mean ----
__global__ __launch_bounds__(256) void mean_xb_pm(const float* __restrict__ x,
                                                  const int* __restrict__ nbr,
                                                  unsigned short* __restrict__ xm,
                                                  int mTot) {
    const int idx = blockIdx.x * 256 + threadIdx.x;
    const int node = idx >> 4;
    const int ch = (idx & 15) * 8;         // 0..120
    const int b = node / NNODES;
    const int n = node - b * NNODES;
    const size_t bbase = (size_t)b * NNODES;
    const int4 nb = *(const int4*)(nbr + (size_t)n * 4);
    const float* ps = x + (size_t)node * 128 + ch;
    union { uint4 v; unsigned short u[8]; } rs, rm;
    float4 a0 = *(const float4*)ps, a1 = *(const float4*)(ps + 4);
    rs.u[0] = f2bf(a0.x); rs.u[1] = f2bf(a0.y); rs.u[2] = f2bf(a0.z); rs.u[3] = f2bf(a0.w);
    rs.u[4] = f2bf(a1.x); rs.u[5] = f2bf(a1.y); rs.u[6] = f2bf(a1.z); rs.u[7] = f2bf(a1.w);
    float s[8] = {0.f, 0.f, 0.f, 0.f, 0.f, 0.f, 0.f, 0.f};
    acc8(x + (bbase + nb.x) * 128 + ch, s);
    acc8(x + (bbase + nb.y) * 128 + ch, s);
    acc8(x + (bbase + nb.z) * 128 + ch, s);
    acc8(x + (bbase + nb.w) * 128 + ch, s);
#pragma unroll
    for (int i = 0; i < 8; ++i) rm.u[i] = f2bf(s[i] * 0.25f);
    const size_t cs = (size_t)mTot * 32;
    *(uint4*)(xm + (size_t)(ch >> 5) * cs + (size_t)node * 32 + (ch & 31)) = rs.v;
    *(uint4*)(xm + (size_t)(4 + (ch >> 5)) * cs + (size_t)node * 32 + (ch & 31)) = rm.v;
}

// ---- hm_pm[c][M][32] = mean4 of h1_pm (phase-major in AND out) ----
__global__ __launch_bounds__(256) void mean_pass_pm(const unsigned short* __restrict__ h1,
                                                    const int* __restrict__ nbr,
                                                    unsigned short* __restrict__ hm,
                                                    int mTot) {
    const int idx = blockIdx.x * 256 + threadIdx.x;
    const int node = idx >> 5;
    const int ch = (idx & 31) * 8;         // 0..248
    const int b = node / NNODES;
    const int n = node - b * NNODES;
    const size_t bbase = (size_t)b * NNODES;
    const int4 nb = *(const int4*)(nbr + (size_t)n * 4);
    const size_t cs = (size_t)mTot * 32;
    const size_t co = (size_t)(ch >> 5) * cs + (ch & 31);
    float s[8] = {0.f, 0.f, 0.f, 0.f, 0.f, 0.f, 0.f, 0.f};
    acc8(h1 + co + (bbase + nb.x) * 32, s);
    acc8(h1 + co + (bbase + nb.y) * 32, s);
    acc8(h1 + co + (bbase + nb.z) * 32, s);
    acc8(h1 + co + (bbase + nb.w) * 32, s);
    union { uint4 v; unsigned short u[8]; } r;
#pragma unroll
    for (int i = 0; i < 8; ++i) r.u[i] = f2bf(s[i] * 0.25f);
    *(uint4*)(hm + co + (size_t)node * 32) = r.v;
}

// ============================================================================
// v15 (round-16 proven best): K=64 phases. NK = K2/64.
//   W: dbuf 2x16KB, staged 1 phase ahead (contiguous 16KB).
//   A: ring 3x16KB, staged 2 phases ahead (2x 8KB contiguous).
//   Uniform vmcnt(4); 0 at end. LDS 80KB -> 2 blocks/CU. Tile 128x128,
//   4 waves; XCD-chunked bijective swizzle; MFMA swapped (wf, af).
// ============================================================================
template <int NK, typename TOUT>
__global__ __launch_bounds__(256) void sage_v15(
    const unsigned short* __restrict__ a0p,   // phase-major A chunks [0,8)
    const unsigned short* __restrict__ a1p,   // phase-major A chunks [8,16)
    const unsigned short* __restrict__ Wp,    // [NK q][256 col][128B] pre-swz
    const float* __restrict__ bias,           // [256]
    TOUT* __restrict__ out,                   // h1_pm (bf16) or [M][256] f32
    int nwg, int mTot) {
    extern __shared__ char lds[];
    const int tid = threadIdx.x;
    const int bid = blockIdx.x;
    const int wk = (bid & 7) * (nwg >> 3) + (bid >> 3);  // bijective (nwg%8==0)
    const int yg = wk & 1;
    const int rb = wk >> 1;
    const int gcol0 = yg * 128;
    const int rowbase = rb * 128;

    const int l = tid & 63, w = tid >> 6;
    const int lr = l & 15, lg = l >> 4;
    const int rowg = w >> 1;          // 2 row groups x 64 rows
    const int colb = (w & 1) * 64;    // 2 col groups x 64 cols

    const size_t chstride = (size_t)mTot * 64;   // bytes per K32 chunk

    auto stageW = [&](int p) {
        char* wb = lds + ((p & 1) << 14);
        const char* src = (const char*)Wp + (size_t)p * 32768 + (size_t)gcol0 * 128;
#pragma unroll
        for (int i = 0; i < 4; ++i) {
            int o = w * 4096 + i * 1024;
            dma16(src + o + l * 16, wb + o + l * 16);
        }
    };
    auto issueA = [&](int p) {
        const char* base = (p >= 4) ? (const char*)a1p : (const char*)a0p;
        const char* src = base + (size_t)((2 * p) & 7) * chstride + (size_t)rowbase * 64;
        char* ring = lds + 32768 + (p % 3) * 16384;
#pragma unroll
        for (int s = 0; s < 2; ++s) {
            const char* cs_ = src + (size_t)s * chstride;
            char* dst = ring + s * 8192;
#pragma unroll
            for (int i = 0; i < 2; ++i) {
                int o = w * 2048 + i * 1024;
                dma16(cs_ + o + l * 16, dst + o + l * 16);
            }
        }
    };

    stageW(0); issueA(0); issueA(1);

    f32x4 acc[4][4];
#pragma unroll
    for (int m = 0; m < 4; ++m)
#pragma unroll
        for (int j = 0; j < 4; ++j) acc[m][j] = (f32x4){0.f, 0.f, 0.f, 0.f};

#pragma unroll
    for (int kk = 0; kk < NK; ++kk) {
        if (kk == NK - 1) { WAIT_VM(0); } else { WAIT_VM(4); }
        __builtin_amdgcn_s_barrier();
        SOFT_FENCE;

        if (kk + 1 < NK) stageW(kk + 1);
        if (kk + 2 < NK) issueA(kk + 2);

        const int ringo = 32768 + (kk % 3) * 16384;
        char* wbuf = lds + ((kk & 1) << 14);
#pragma unroll
        for (int sub = 0; sub < 2; ++sub) {
            short8 af[4];
#pragma unroll
            for (int m = 0; m < 4; ++m)
                af[m] = *(const short8*)(lds + ringo + sub * 8192 +
                                         ((rowg * 4 + m) * 16 + lr) * 64 + lg * 16);
            const int kq0 = (sub << 6) | (lg << 4);
#pragma unroll
            for (int j = 0; j < 4; ++j) {
                const int col = colb + j * 16 + lr;
                const short8 wf = *(const short8*)(
                    wbuf + (col << 7) + (kq0 ^ ((lr & 7) << 4)));
#pragma unroll
                for (int m = 0; m < 4; ++m)
                    acc[m][j] = __builtin_amdgcn_mfma_f32_16x16x32_bf16(wf, af[m], acc[m][j], 0, 0, 0);
            }
        }
        SOFT_FENCE;
    }

    // epilogue (swapped layout): lane holds 4 consecutive cols
#pragma unroll
    for (int m = 0; m < 4; ++m) {
        const int row = rowbase + rowg * 64 + m * 16 + lr;
#pragma unroll
        for (int j = 0; j < 4; ++j) {
            const int gcol = gcol0 + colb + j * 16 + lg * 4;
            const float4 bv = *(const float4*)(bias + gcol);
            float o0 = fmaxf(acc[m][j][0] + bv.x, 0.f);
            float o1 = fmaxf(acc[m][j][1] + bv.y, 0.f);
            float o2 = fmaxf(acc[m][j][2] + bv.z, 0.f);
            float o3 = fmaxf(acc[m][j][3] + bv.w, 0.f);
            if constexpr (sizeof(TOUT) == 4) {
                float4 o = {o0, o1, o2, o3};
                *(float4*)((float*)out + (size_t)row * 256 + gcol) = o;
            } else {
                union { unsigned short u[4]; uint2 v; } pk;
                pk.u[0] = f2bf(o0); pk.u[1] = f2bf(o1);
                pk.u[2] = f2bf(o2); pk.u[3] = f2bf(o3);
                unsigned short* hp = (unsigned short*)out +
                    (size_t)(gcol >> 5) * ((size_t)mTot * 32) +
                    (size_t)row * 32 + (gcol & 31);
                *(uint2*)hp = pk.v;
            }
        }
    }
}

// ---- v3 fallback (small ws): fused gather, weights all-K in LDS ----
template <int C, typename TIN, typename TOUT>
__global__ __launch_bounds__(512, 2) void sage_v3(
    const TIN* __restrict__ hin, const int* __restrict__ nbr,
    const unsigned short* __restrict__ Wt, const float* __restrict__ bias,
    TOUT* __restrict__ out) {
    constexpr int K2 = 2 * C;
    constexpr int ROWB = K2 * 2;
    constexpr int LCOLS = 131072 / ROWB;
    constexpr int CG = LCOLS / 128;
    constexpr int RG = 8 / CG;
    extern __shared__ char Bs[];

    const int tid = threadIdx.x;
    const int gcol0 = blockIdx.y * LCOLS;
    {
        const char* src = (const char*)(Wt + (size_t)gcol0 * K2);
#pragma unroll
        for (int i = 0; i < 16; ++i) {
            int byt = (i * 512 + tid) * 16;
            uint4 v = *(const uint4*)(src + byt);
            int c = byt / ROWB;
            *(uint4*)(Bs + (byt ^ ((c & 7) << 4))) = v;
        }
    }
    __syncthreads();

    const int l = tid & 63;
    const int w = tid >> 6;
    const int rowg = w / CG;
    const int colb = (w % CG) * 128;
    const int lr = l & 15, lg = l >> 4;

    const int rowbase = blockIdx.x * (RG * 64) + rowg * 64;
    const int bb = rowbase / NNODES;
    const int n0 = rowbase - bb * NNODES;
    const size_t bbase = (size_t)bb * NNODES;

    unsigned soff[4], noff[4][4];
#pragma unroll
    for (int m = 0; m < 4; ++m) {
        int r = m * 16 + lr;
        soff[m] = (unsigned)(((rowbase + r) * (size_t)C + lg * 8) * sizeof(TIN));
        int4 nb = *(const int4*)(nbr + (size_t)(n0 + r) * 4);
        noff[m][0] = (unsigned)(((bbase + nb.x) * C + lg * 8) * sizeof(TIN));
        noff[m][1] = (unsigned)(((bbase + nb.y) * C + lg * 8) * sizeof(TIN));
        noff[m][2] = (unsigned)(((bbase + nb.z) * C + lg * 8) * sizeof(TIN));
        noff[m][3] = (unsigned)(((bbase + nb.w) * C + lg * 8) * sizeof(TIN));
    }
    const char* hb = (const char*)hin;

    f32x4 acc[4][8];
#pragma unroll
    for (int m = 0; m < 4; ++m)
#pragma unroll
        for (int j = 0; j < 8; ++j) acc[m][j] = (f32x4){0.f, 0.f, 0.f, 0.f};

#pragma unroll
    for (int kk = 0; kk < K2 / 32; ++kk) {
        const int k0 = kk * 32;
        short8 a[4];
        if (k0 < C) {
            const unsigned kb = k0 * sizeof(TIN);
#pragma unroll
            for (int m = 0; m < 4; ++m)
                a[m] = frag_self((const TIN*)(hb + soff[m] + kb));
        } else {
            const unsigned kb = (k0 - C) * sizeof(TIN);
#pragma unroll
            for (int m = 0; m < 4; ++m)
                a[m] = frag_mean4((const TIN*)(hb + noff[m][0] + kb),
                                  (const TIN*)(hb + noff[m][1] + kb),
                                  (const TIN*)(hb + noff[m][2] + kb),
                                  (const TIN*)(hb + noff[m][3] + kb));
        }
#pragma unroll
        for (int j = 0; j < 8; ++j) {
            const int c = colb + j * 16 + lr;
            const short8 bf = *(const short8*)(
                Bs + ((c * ROWB + (k0 + lg * 8) * 2) ^ ((l & 7) << 4)));
#pragma unroll
            for (int m = 0; m < 4; ++m)
                acc[m][j] = __builtin_amdgcn_mfma_f32_16x16x32_bf16(a[m], bf, acc[m][j], 0, 0, 0);
        }
    }

#pragma unroll
    for (int j = 0; j < 8; ++j) {
        const int gcol = gcol0 + colb + j * 16 + lr;
        const float bv = bias[gcol];
#pragma unroll
        for (int m = 0; m < 4; ++m) {
#pragma unroll
            for (int r = 0; r < 4; ++r) {
                const int row = rowbase + m * 16 + lg * 4 + r;
                storev(out + (size_t)row * DOUT + gcol, fmaxf(acc[m][j][r] + bv, 0.f));
            }
        }
    }
}

extern "C" void kernel_launch(void* const* d_in, const int* in_sizes, int n_in,
                              void* d_out, int out_size, void* d_ws, size_t ws_size,
                              hipStream_t stream) {
    const float* x = (const float*)d_in[0];
    const int* nbr = (const int*)d_in[1];
    const float* Ws1 = (const float*)d_in[2];
    const float* Wn1 = (const float*)d_in[3];
    const float* b1 = (const float*)d_in[4];
    const float* Ws2 = (const float*)d_in[5];
    const float* Wn2 = (const float*)d_in[6];
    const float* b2 = (const float*)d_in[7];
    float* out = (float*)d_out;

    const int B = in_sizes[0] / (NNODES * 128);  // 4
    const int M = B * NNODES;                    // 221184

    char* ws = (char*)d_ws;
    const size_t h1_bytes = (size_t)M * DOUT * 2;
    const size_t hm_bytes = (size_t)M * DOUT * 2;  // xm_pm for L1, then hm_pm for L2
    const size_t need = h1_bytes + hm_bytes + 131072 + 262144;

    if (ws_size >= need) {
        unsigned short* h1 = (unsigned short*)ws;                       // phase-major
        unsigned short* xm = (unsigned short*)(ws + h1_bytes);          // pm; reused hm
        unsigned short* W1p = (unsigned short*)(ws + h1_bytes + hm_bytes);
        unsigned short* W2p = W1p + 256 * 256;

        build_wt_pm<<<256, 256, 0, stream>>>(Ws1, Wn1, W1p, 128);
        build_wt_pm<<<512, 256, 0, stream>>>(Ws2, Wn2, W2p, 256);

        hipFuncSetAttribute((const void*)sage_v15<4, unsigned short>,
                            hipFuncAttributeMaxDynamicSharedMemorySize, 81920);
        hipFuncSetAttribute((const void*)sage_v15<8, float>,
                            hipFuncAttributeMaxDynamicSharedMemorySize, 81920);

        const int nwg = (M / 128) * 2;  // 3456, divisible by 8

        // layer 1: xm_pm = [bf16(x) | mean4(x)] phase-major; K2=256 GEMM (4 phases)
        mean_xb_pm<<<M / 16, 256, 0, stream>>>(x, nbr, xm, M);
        sage_v15<4, unsigned short>
            <<<nwg, 256, 81920, stream>>>(xm, xm, W1p, b1, h1, nwg, M);
        // layer 2: hm_pm overwrites xm; K2=512 GEMM (8 phases, A = h1_pm then hm_pm)
        mean_pass_pm<<<M / 8, 256, 0, stream>>>(h1, nbr, xm, M);
        sage_v15<8, float>
            <<<nwg, 256, 81920, stream>>>(h1, xm, W2p, b2, out, nwg, M);
    } else {
        unsigned short* h1 = (unsigned short*)ws;
        unsigned short* Wt1 = (unsigned short*)(ws + h1_bytes);
        unsigned short* Wt2 = Wt1 + 256 * 256;

        build_wt<<<256, 256, 0, stream>>>(Ws1, Wn1, Wt1, 128);
        build_wt<<<512, 256, 0, stream>>>(Ws2, Wn2, Wt2, 256);

        hipFuncSetAttribute((const void*)sage_v3<128, float, unsigned short>,
                            hipFuncAttributeMaxDynamicSharedMemorySize, 131072);
        hipFuncSetAttribute((const void*)sage_v3<256, unsigned short, float>,
                            hipFuncAttributeMaxDynamicSharedMemorySize, 131072);

        sage_v3<128, float, unsigned short>
            <<<dim3(M / 256, 1), 512, 131072, stream>>>(x, nbr, Wt1, b1, h1);
        sage_v3<256, unsigned short, float>
            <<<dim3(M / 512, 2), 512, 131072, stream>>>(h1, nbr, Wt2, b2, out);
    }
}